// Round 9
// baseline (277.745 us; speedup 1.0000x reference)
//
#include <hip/hip_runtime.h>
#include <math.h>

#define CIN 128
#define HD  96
#define SP  3136   // 56*56
#define ROW 56
#define SLAB 1568  // 28*56

// ---------------- Kernel 0: transpose W into Wt[c][o] (o<96: Wc, else Wp) ----------------
__global__ __launch_bounds__(256) void wt_k(
    const float* __restrict__ Wc, const float* __restrict__ Wp,
    float* __restrict__ Wt)
{
  const int idx = blockIdx.x * 256 + threadIdx.x;   // 0..24575
  if (idx >= 128 * 192) return;
  const int c = idx / 192, o = idx - c * 192;
  Wt[idx] = (o < 96) ? Wc[(size_t)o * CIN + c] : Wp[(size_t)(o - 96) * CIN + c];
}

// ---------------- Kernel 1: q/value 1x1 conv — LDS-free, anti-fission, batch-8 loads ----------------
// 4 waves/block; wave w owns outputs [w*48, w*48+48); lane = spatial column.
__global__ __launch_bounds__(256) void qv_conv(
    const float* __restrict__ x, const float* __restrict__ Wt,
    const float* __restrict__ bc, const float* __restrict__ bp,
    float* __restrict__ qbuf, float* __restrict__ vbuf)
{
  const int st = blockIdx.x % 49;
  const int b  = blockIdx.x / 49;
  const int tid = threadIdx.x;
  const int lane = tid & 63;
  const int wq = __builtin_amdgcn_readfirstlane(tid >> 6);   // 0..3, wave-uniform
  const float* xg = x + (size_t)b * CIN * SP + st * 64 + lane;
  const float* wbase = Wt + wq * 48;

  float acc[48];
  #pragma unroll
  for (int i = 0; i < 48; ++i) acc[i] = 0.f;

  #pragma unroll 2
  for (int c0 = 0; c0 < CIN; c0 += 8) {
    float xv[8];
    // issue 8 independent coalesced loads (8 outstanding per wave)
    #pragma unroll
    for (int u = 0; u < 8; ++u) xv[u] = xg[(size_t)(c0 + u) * SP];
    // opaque volatile pass-through: cannot be duplicated/rematerialized ->
    // blocks loop fission of the FMA groups (keeps ONE fused loop, 48 live acc)
    #pragma unroll
    for (int u = 0; u < 8; ++u) asm volatile("" : "+v"(xv[u]));
    #pragma unroll
    for (int u = 0; u < 8; ++u) {
      const float4* wr = reinterpret_cast<const float4*>(wbase + (size_t)(c0 + u) * 192);
      #pragma unroll
      for (int j = 0; j < 12; ++j) {
        const float4 w4 = wr[j];                             // uniform -> s_load_dwordx4
        acc[j*4+0] = fmaf(w4.x, xv[u], acc[j*4+0]);
        acc[j*4+1] = fmaf(w4.y, xv[u], acc[j*4+1]);
        acc[j*4+2] = fmaf(w4.z, xv[u], acc[j*4+2]);
        acc[j*4+3] = fmaf(w4.w, xv[u], acc[j*4+3]);
      }
    }
  }

  if (wq < 2) {          // q waves: outputs 0..95
    const int o0 = wq * 48;
    #pragma unroll
    for (int i = 0; i < 48; ++i) {
      const int o = o0 + i;
      qbuf[((size_t)b * 96 + o) * SP + st * 64 + lane] = acc[i] + bc[o];
    }
  } else {               // v waves: outputs 96..191 -> v channels 0..95
    const int o0 = wq * 48 - 96;
    #pragma unroll
    for (int i = 0; i < 48; ++i) {
      const int o = o0 + i;
      vbuf[((size_t)b * 96 + o) * SP + st * 64 + lane] = acc[i] + bp[o];
    }
  }
}

// ---------------- Kernel 2: clustering per (b,e,f1); exports s/g/clf into dead q ----------------
__global__ __launch_bounds__(512, 4) void cluster_k(
    float* qbuf, const float* __restrict__ vbuf,
    const float* __restrict__ alpha_p, const float* __restrict__ beta_p)
{
  const int blk = blockIdx.x;              // (b*4+e)*2 + f1
  const int f1  = blk & 1;
  const int be  = blk >> 1;
  const size_t base = (size_t)be * 24 * SP + (size_t)(f1 * 28) * ROW;
  float* qp = qbuf + base;
  const float* vp = vbuf + base;

  __shared__ double cnd[24][8];
  __shared__ float  sbest[SLAB];
  __shared__ unsigned char ibest[SLAB];
  __shared__ float  clr[8][24];
  __shared__ float  vcr[8][24];
  __shared__ float  dnf[8];

  const int tid  = threadIdx.x;
  const int wid  = tid >> 6;
  const int lane = tid & 63;

  for (int c = wid; c < 24; c += 8) {
    const float* src = qp + (size_t)c * SP;
    double b0=0,b1=0,b2=0,b3=0,b4=0,b5=0,b6=0,b7=0;
    for (int n = lane; n < SLAB; n += 64) {
      const int w = n / 56, h = n - w * 56;
      const int hf = (h >= 28) ? (h - 28) : h;
      const int g  = ((h >= 28) ? 4 : 0) + ((w >= 14) ? 2 : 0) + ((hf >= 14) ? 1 : 0);
      const double val = (double)src[n];
      b0 += (g==0)?val:0.0; b1 += (g==1)?val:0.0;
      b2 += (g==2)?val:0.0; b3 += (g==3)?val:0.0;
      b4 += (g==4)?val:0.0; b5 += (g==5)?val:0.0;
      b6 += (g==6)?val:0.0; b7 += (g==7)?val:0.0;
    }
    #pragma unroll
    for (int m = 32; m >= 1; m >>= 1) {
      b0 += __shfl_xor(b0,m); b1 += __shfl_xor(b1,m);
      b2 += __shfl_xor(b2,m); b3 += __shfl_xor(b3,m);
      b4 += __shfl_xor(b4,m); b5 += __shfl_xor(b5,m);
      b6 += __shfl_xor(b6,m); b7 += __shfl_xor(b7,m);
    }
    if (lane == 0) {
      cnd[c][0]=b0*(1.0/196.0); cnd[c][1]=b1*(1.0/196.0);
      cnd[c][2]=b2*(1.0/196.0); cnd[c][3]=b3*(1.0/196.0);
      cnd[c][4]=b4*(1.0/196.0); cnd[c][5]=b5*(1.0/196.0);
      cnd[c][6]=b6*(1.0/196.0); cnd[c][7]=b7*(1.0/196.0);
    }
  }
  __syncthreads();
  if (tid < 8) {
    double s = 0.0;
    #pragma unroll
    for (int c = 0; c < 24; ++c) { double t = cnd[c][tid]; s += t * t; }
    const double inv = 1.0 / fmax(sqrt(s), 1e-12);
    #pragma unroll
    for (int c = 0; c < 24; ++c) cnd[c][tid] *= inv;
  }
  __syncthreads();

  const double alpha = (double)alpha_p[0];
  const double beta  = (double)beta_p[0];

  for (int n0 = tid; n0 < SLAB; n0 += 512) {
    const int h  = n0 % 56;
    const int gb = (h >= 28) ? 4 : 0;
    double z0=0,z1=0,z2=0,z3=0,nrm=0;
    for (int c = 0; c < 24; ++c) {
      const double qv = (double)qp[(size_t)c * SP + n0];
      z0 += cnd[c][gb+0]*qv; z1 += cnd[c][gb+1]*qv;
      z2 += cnd[c][gb+2]*qv; z3 += cnd[c][gb+3]*qv;
      nrm += qv*qv;
    }
    const double inv = 1.0 / fmax(sqrt(nrm), 1e-12);
    const double v0 = beta + alpha * (z0 * inv);
    const double v1 = beta + alpha * (z1 * inv);
    const double v2 = beta + alpha * (z2 * inv);
    const double v3 = beta + alpha * (z3 * inv);
    double zb = v0; int bi = 0;
    if (v1 > zb) { zb = v1; bi = 1; }
    if (v2 > zb) { zb = v2; bi = 2; }
    if (v3 > zb) { zb = v3; bi = 3; }
    sbest[n0] = (float)(1.0 / (1.0 + exp(-zb)));
    ibest[n0] = (unsigned char)(gb + bi);
  }
  __syncthreads();

  for (int c = wid; c < 24; c += 8) {
    const float* vsrc = vp + (size_t)c * SP;
    float cl0=0,cl1=0,cl2=0,cl3=0,cl4=0,cl5=0,cl6=0,cl7=0;
    float vc0=0,vc1=0,vc2=0,vc3=0,vc4=0,vc5=0,vc6=0,vc7=0;
    float dn0=0,dn1=0,dn2=0,dn3=0,dn4=0,dn5=0,dn6=0,dn7=0;
    for (int n = lane; n < SLAB; n += 64) {
      const int w = n / 56, h = n - w * 56;
      const int hf = (h >= 28) ? (h - 28) : h;
      const int fb = (h >= 28) ? 4 : 0;
      const float v = vsrc[n];
      const float s = sbest[n];
      const int gi = ibest[n];
      const int gm = fb + ((w >= 14) ? 2 : 0) + ((hf >= 14) ? 1 : 0);
      const float sv = s * v;
      cl0 += (gi==0)?sv:0.f; cl1 += (gi==1)?sv:0.f;
      cl2 += (gi==2)?sv:0.f; cl3 += (gi==3)?sv:0.f;
      cl4 += (gi==4)?sv:0.f; cl5 += (gi==5)?sv:0.f;
      cl6 += (gi==6)?sv:0.f; cl7 += (gi==7)?sv:0.f;
      vc0 += (gm==0)?v:0.f;  vc1 += (gm==1)?v:0.f;
      vc2 += (gm==2)?v:0.f;  vc3 += (gm==3)?v:0.f;
      vc4 += (gm==4)?v:0.f;  vc5 += (gm==5)?v:0.f;
      vc6 += (gm==6)?v:0.f;  vc7 += (gm==7)?v:0.f;
      dn0 += (gi==0)?s:0.f;  dn1 += (gi==1)?s:0.f;
      dn2 += (gi==2)?s:0.f;  dn3 += (gi==3)?s:0.f;
      dn4 += (gi==4)?s:0.f;  dn5 += (gi==5)?s:0.f;
      dn6 += (gi==6)?s:0.f;  dn7 += (gi==7)?s:0.f;
    }
    #pragma unroll
    for (int m = 32; m >= 1; m >>= 1) {
      cl0 += __shfl_xor(cl0,m); cl1 += __shfl_xor(cl1,m);
      cl2 += __shfl_xor(cl2,m); cl3 += __shfl_xor(cl3,m);
      cl4 += __shfl_xor(cl4,m); cl5 += __shfl_xor(cl5,m);
      cl6 += __shfl_xor(cl6,m); cl7 += __shfl_xor(cl7,m);
      vc0 += __shfl_xor(vc0,m); vc1 += __shfl_xor(vc1,m);
      vc2 += __shfl_xor(vc2,m); vc3 += __shfl_xor(vc3,m);
      vc4 += __shfl_xor(vc4,m); vc5 += __shfl_xor(vc5,m);
      vc6 += __shfl_xor(vc6,m); vc7 += __shfl_xor(vc7,m);
      dn0 += __shfl_xor(dn0,m); dn1 += __shfl_xor(dn1,m);
      dn2 += __shfl_xor(dn2,m); dn3 += __shfl_xor(dn3,m);
      dn4 += __shfl_xor(dn4,m); dn5 += __shfl_xor(dn5,m);
      dn6 += __shfl_xor(dn6,m); dn7 += __shfl_xor(dn7,m);
    }
    if (lane == 0) {
      clr[0][c]=cl0; clr[1][c]=cl1; clr[2][c]=cl2; clr[3][c]=cl3;
      clr[4][c]=cl4; clr[5][c]=cl5; clr[6][c]=cl6; clr[7][c]=cl7;
      vcr[0][c]=vc0*(1.f/196.f); vcr[1][c]=vc1*(1.f/196.f);
      vcr[2][c]=vc2*(1.f/196.f); vcr[3][c]=vc3*(1.f/196.f);
      vcr[4][c]=vc4*(1.f/196.f); vcr[5][c]=vc5*(1.f/196.f);
      vcr[6][c]=vc6*(1.f/196.f); vcr[7][c]=vc7*(1.f/196.f);
      if (c == 0) {
        dnf[0]=dn0; dnf[1]=dn1; dnf[2]=dn2; dnf[3]=dn3;
        dnf[4]=dn4; dnf[5]=dn5; dnf[6]=dn6; dnf[7]=dn7;
      }
    }
  }
  __syncthreads();

  if (tid < 192) {
    const int g = tid / 24, c = tid - g * 24;
    qp[2 * (size_t)SP + tid] = (clr[g][c] + vcr[g][c]) / (dnf[g] + 1.0f);
  }
  for (int i = tid; i < SLAB; i += 512) {
    qp[i] = sbest[i];
    reinterpret_cast<unsigned int*>(qp + SP)[i] = (unsigned int)ibest[i];
  }
}

// ---------------- Kernel 2b: proj[e*8+g][co] = Wo_e[co] . clf_e[g]  per (b,f1,e) ----------------
__global__ __launch_bounds__(256) void proj_k(
    float* qbuf, const float* __restrict__ Wo)
{
  const int bid = blockIdx.x;           // ((b*2+f1)*4 + e)
  const int e   = bid & 3;
  const int f1  = (bid >> 2) & 1;
  const int b   = bid >> 3;
  const float* clfg = qbuf + ((size_t)(b*4 + e) * 24 + 2) * SP + (size_t)(f1*28) * ROW;
  float* projb = qbuf + ((size_t)b * 96 + 3 + f1*3) * SP;

  __shared__ float clfs[8][24];
  const int tid = threadIdx.x;
  if (tid < 192) clfs[tid / 24][tid % 24] = clfg[tid];
  __syncthreads();

  const int co = tid & 127;
  const int kh = tid >> 7;
  float wo_r[24];
  #pragma unroll
  for (int c = 0; c < 24; ++c) wo_r[c] = Wo[(size_t)co * HD + e*24 + c];
  #pragma unroll
  for (int t = 0; t < 4; ++t) {
    const int g = kh * 4 + t;
    float s = 0.f;
    #pragma unroll
    for (int c = 0; c < 24; ++c) s = fmaf(wo_r[c], clfs[g][c], s);
    projb[((size_t)e * 8 + g) * 128 + co] = s;
  }
}

// ---------------- Kernel 3: output via proj lookup; per (b,f1,rowpair) ----------------
__global__ __launch_bounds__(256) void out_k(
    const float* __restrict__ qbuf, const float* __restrict__ bo,
    float* __restrict__ out)
{
  const int bid = blockIdx.x;           // (b*2+f1)*14 + rp
  const int b   = bid / 28;
  const int rem = bid % 28;
  const int f1  = rem / 14;
  const int rp  = rem % 14;
  const int n0  = rp * 112;

  __shared__ float  proj_l[4096];
  __shared__ float4 s_l4[112];
  __shared__ unsigned int g_l[112];
  __shared__ float  out_l[56 * 132];

  const int tid = threadIdx.x;

  {
    const float4* pg = reinterpret_cast<const float4*>(
        qbuf + ((size_t)b * 96 + 3 + f1*3) * SP);
    float4* pl = reinterpret_cast<float4*>(proj_l);
    #pragma unroll
    for (int r = 0; r < 4; ++r) pl[tid + r * 256] = pg[tid + r * 256];
  }
  for (int i = tid; i < 112; i += 256) {
    float4 sv; unsigned int gp = 0;
    #pragma unroll
    for (int e = 0; e < 4; ++e) {
      const float* sp = qbuf + ((size_t)(b*4 + e) * 24) * SP + (size_t)(f1*28) * ROW;
      const float sval = sp[n0 + i];
      const unsigned int gv = reinterpret_cast<const unsigned int*>(sp + SP)[n0 + i];
      if (e == 0) sv.x = sval; else if (e == 1) sv.y = sval;
      else if (e == 2) sv.z = sval; else sv.w = sval;
      gp |= (gv & 7u) << (8 * e);
    }
    s_l4[i] = sv; g_l[i] = gp;
  }
  __syncthreads();

  const int cq  = tid & 31;
  const int sub = tid >> 5;
  const float4 bo4 = *reinterpret_cast<const float4*>(bo + cq * 4);
  const float4* pl4 = reinterpret_cast<const float4*>(proj_l);

  for (int chunk = 0; chunk < 2; ++chunk) {
    const int pbase = chunk * 56;
    #pragma unroll
    for (int i = 0; i < 7; ++i) {
      const int pxl = sub * 7 + i;
      const int px  = pbase + pxl;
      const float4 sv = s_l4[px];
      const unsigned int gp = g_l[px];
      float4 acc = bo4;
      {
        const float4 p = pl4[(0*8 + (gp        & 7u)) * 32 + cq];
        acc.x = fmaf(sv.x, p.x, acc.x); acc.y = fmaf(sv.x, p.y, acc.y);
        acc.z = fmaf(sv.x, p.z, acc.z); acc.w = fmaf(sv.x, p.w, acc.w);
      }
      {
        const float4 p = pl4[(1*8 + ((gp >> 8) & 7u)) * 32 + cq];
        acc.x = fmaf(sv.y, p.x, acc.x); acc.y = fmaf(sv.y, p.y, acc.y);
        acc.z = fmaf(sv.y, p.z, acc.z); acc.w = fmaf(sv.y, p.w, acc.w);
      }
      {
        const float4 p = pl4[(2*8 + ((gp >> 16) & 7u)) * 32 + cq];
        acc.x = fmaf(sv.z, p.x, acc.x); acc.y = fmaf(sv.z, p.y, acc.y);
        acc.z = fmaf(sv.z, p.z, acc.z); acc.w = fmaf(sv.z, p.w, acc.w);
      }
      {
        const float4 p = pl4[(3*8 + ((gp >> 24) & 7u)) * 32 + cq];
        acc.x = fmaf(sv.w, p.x, acc.x); acc.y = fmaf(sv.w, p.y, acc.y);
        acc.z = fmaf(sv.w, p.z, acc.z); acc.w = fmaf(sv.w, p.w, acc.w);
      }
      *reinterpret_cast<float4*>(&out_l[pxl * 132 + cq * 4]) = acc;
    }
    __syncthreads();
    for (int t = tid; t < 128 * 56; t += 256) {
      const int co = t / 56, pxl = t - co * 56;
      out[((size_t)b * 128 + co) * SP + (size_t)f1 * SLAB + n0 + pbase + pxl] =
          out_l[pxl * 132 + co];
    }
    __syncthreads();
  }
}

extern "C" void kernel_launch(void* const* d_in, const int* in_sizes, int n_in,
                              void* d_out, int out_size, void* d_ws, size_t ws_size,
                              hipStream_t stream) {
  const float* x  = (const float*)d_in[0];
  const float* Wc = (const float*)d_in[1];
  const float* bc = (const float*)d_in[2];
  const float* Wp = (const float*)d_in[3];
  const float* bp = (const float*)d_in[4];
  const float* sa = (const float*)d_in[5];
  const float* sb = (const float*)d_in[6];
  const float* Wo = (const float*)d_in[7];
  const float* bo = (const float*)d_in[8];
  float* out  = (float*)d_out;
  float* qbuf = (float*)d_ws;                       // 77.1 MB
  float* vbuf = out;                                // v scratch in d_out, overwritten by out_k
  float* wt   = out + (size_t)64 * 96 * SP;         // 98 KB in dead d_out space past vbuf

  wt_k<<<dim3(96), dim3(256), 0, stream>>>(Wc, Wp, wt);
  qv_conv<<<dim3(64 * 49), dim3(256), 0, stream>>>(x, wt, bc, bp, qbuf, vbuf);
  cluster_k<<<dim3(512), dim3(512), 0, stream>>>(qbuf, vbuf, sa, sb);
  proj_k<<<dim3(512), dim3(256), 0, stream>>>(qbuf, Wo);
  out_k<<<dim3(1792), dim3(256), 0, stream>>>(qbuf, bo, out);
}